// Round 12
// baseline (502.233 us; speedup 1.0000x reference)
//
#include <hip/hip_runtime.h>
#include <stdint.h>

#define N_NODES 2048
#define N_EDGES 4096
#define N_GRAPH 16
#define IN_DIM  11
#define HID     128
#define E_DIMF  6
#define EDGE_H  64
#define NSLICE  65            // 64 h-slices + 1 bias slice (h==1)
#define BN_EPS  1e-5f

typedef __attribute__((ext_vector_type(8))) short short8;
typedef __attribute__((ext_vector_type(4))) float f32x4;

static __device__ __forceinline__ float bf2f(unsigned short u) {
  union { float f; uint32_t i; } x; x.i = ((uint32_t)u) << 16; return x.f;
}
static __device__ __forceinline__ unsigned short f2bf(float f) {
  union { float f; uint32_t i; } x; x.f = f;
  uint32_t i = x.i;
  return (unsigned short)((i + 0x7FFFu + ((i >> 16) & 1u)) >> 16);
}

// direct global->LDS DMA, 16B per lane. LDS dest must be base+lane*16 (linear).
static __device__ __forceinline__ void gload_lds16(const void* g, void* l) {
  __builtin_amdgcn_global_load_lds(
      (const __attribute__((address_space(1))) uint32_t*)g,
      (__attribute__((address_space(3))) uint32_t*)l, 16, 0, 0);
}

struct PrepP {
  const float *eW2_0, *eb2_0, *eW2, *eb2;
  const int *dst;
  const float *bias_0, *gamma_0, *beta_0, *mean_0, *var_0;
  const float *biasL, *gammaL, *betaL, *meanL, *varL;
  unsigned short *Wt0, *WtL;
  int *roff, *cursor;
  float *invdeg;
  f32x4 *bnp;       // [4][128]: {bias, S=gamma*rsqrt(var+eps), T=beta-mean*S, 0}
  float *aggs;      // [4][N][HID] fp32, zeroed
  float *gsum;
  unsigned int *gmax;
  float *gcnt;
};

// == prep_all: CSR(0) + Wt transposes(1..260) + agg zero(261..292) + misc(293) ==
#define PREP_BLOCKS 294
__global__ __launch_bounds__(256) void prep_all(PrepP p) {
  const int bid = blockIdx.x, t = threadIdx.x;
  __shared__ union {
    struct { int hist[N_NODES]; int part[256]; } csr;       // 9 KB
    unsigned short tile[128 * 130];                          // 33.3 KB
  } sm;

  if (bid == 0) {
    // ---- deg histogram + exclusive scan -> roff, cursor, invdeg ----
    for (int i = t; i < N_NODES; i += 256) sm.csr.hist[i] = 0;
    __syncthreads();
    for (int e = t; e < N_EDGES; e += 256) atomicAdd(&sm.csr.hist[p.dst[e]], 1);
    __syncthreads();
    const int base = t * 8;
    int loc[8];
    int s = 0;
#pragma unroll
    for (int j = 0; j < 8; ++j) { loc[j] = s; s += sm.csr.hist[base + j]; }
    sm.csr.part[t] = s;
    __syncthreads();
    for (int d = 1; d < 256; d <<= 1) {  // Hillis-Steele inclusive scan
      int v = sm.csr.part[t];
      if (t >= d) v += sm.csr.part[t - d];
      __syncthreads();
      sm.csr.part[t] = v;
      __syncthreads();
    }
    const int pre = (t == 0) ? 0 : sm.csr.part[t - 1];
#pragma unroll
    for (int j = 0; j < 8; ++j) {
      p.roff[base + j] = pre + loc[j];
      p.cursor[base + j] = pre + loc[j];
      p.invdeg[base + j] = 1.f / fmaxf((float)sm.csr.hist[base + j], 1.f);
    }
    if (t == 255) p.roff[N_NODES] = pre + s;
  } else if (bid <= 260) {
    // ---- transpose one W2 slab -> Wt[o][k][i] bf16 ----
    const int s = bid - 1;
    if (s < 65) {  // layer 0: KP=32, din=11
      const int k = s;
      const float* srcp = (k < 64) ? (p.eW2_0 + (size_t)k * IN_DIM * HID) : p.eb2_0;
      for (int j = t; j < IN_DIM * HID; j += 256) {
        int i = j >> 7, o = j & 127;
        sm.tile[i * 130 + o] = f2bf(srcp[j]);
      }
      __syncthreads();
      for (int j = t; j < HID * 32; j += 256) {
        int o = j >> 5, i = j & 31;
        p.Wt0[((size_t)o * NSLICE + k) * 32 + i] =
            (i < IN_DIM) ? sm.tile[i * 130 + o] : (unsigned short)0;
      }
    } else {  // layers 1..3: KP=128
      const int sl = s - 65, l = sl / 65, k = sl % 65;
      const float* srcp = (k < 64) ? (p.eW2 + ((size_t)l * 64 + k) * (HID * HID))
                                   : (p.eb2 + (size_t)l * (HID * HID));
      unsigned short* dstp = p.WtL + (size_t)l * HID * NSLICE * HID;
      for (int j = t; j < HID * HID; j += 256) {
        int i = j >> 7, o = j & 127;
        sm.tile[i * 130 + o] = f2bf(srcp[j]);
      }
      __syncthreads();
      for (int j = t; j < HID * HID; j += 256) {
        int o = j >> 7, i = j & 127;
        dstp[((size_t)o * NSLICE + k) * HID + i] = sm.tile[i * 130 + o];
      }
    }
  } else if (bid <= 292) {
    // ---- zero the 4 agg buffers (4 MB over 32 blocks) ----
    const int per = 4 * N_NODES * HID / 32;  // 32768 floats per block
    float* z = p.aggs + (size_t)(bid - 261) * per;
    for (int i = t; i < per; i += 256) z[i] = 0.f;
  } else {
    // ---- zero readout accums + compute folded BN params ----
    for (int i = t; i < N_GRAPH * HID; i += 256) {
      p.gsum[i] = 0.f;
      p.gmax[i] = 0u;
    }
    if (t < N_GRAPH) p.gcnt[t] = 0.f;
    if (t < HID) {
#pragma unroll
      for (int l = 0; l < 4; ++l) {
        float bb, ga, be, mu, vv;
        if (l == 0) {
          bb = p.bias_0[t]; ga = p.gamma_0[t]; be = p.beta_0[t];
          mu = p.mean_0[t]; vv = p.var_0[t];
        } else {
          const int q = (l - 1) * HID + t;
          bb = p.biasL[q]; ga = p.gammaL[q]; be = p.betaL[q];
          mu = p.meanL[q]; vv = p.varL[q];
        }
        const float S = ga * rsqrtf(vv + BN_EPS);
        f32x4 r;
        r.x = bb; r.y = S; r.z = be - mu * S; r.w = 0.f;
        p.bnp[l * HID + t] = r;
      }
    }
  }
}

// ==== scatter_pg: parallel scatter + pre-gather esrc/ef6 (dst-sorted) =========
__global__ __launch_bounds__(256) void scatter_pg(const int* __restrict__ dst,
                                                  const int* __restrict__ srcv,
                                                  const float* __restrict__ efeat,
                                                  int* __restrict__ cursor,
                                                  int* __restrict__ esrc,
                                                  float* __restrict__ ef6) {
  const int e = blockIdx.x * 256 + threadIdx.x;
  if (e >= N_EDGES) return;
  float ef[E_DIMF];
#pragma unroll
  for (int j = 0; j < E_DIMF; ++j) ef[j] = efeat[e * E_DIMF + j];
  const int se = srcv[e];
  const int pos = atomicAdd(&cursor[dst[e]], 1);
  esrc[pos] = se;
#pragma unroll
  for (int j = 0; j < E_DIMF; ++j) ef6[pos * E_DIMF + j] = ef[j];
}

// ==== fused_layer: split-K gather-GEMM ========================================
// agg_out[n,o] += sum_{k,i} A[n,k,i] * Wt[o,k,i], A[n,k,i] = sum_{e->n} h[e,k]*X[src,i]
// grid (13 K-chunks, 32 M-tiles of 64 nodes), 256 threads.
// Per k-slice: stage B-slab [128 o][KP i] via global_load_lds (pre-swz source);
// build A-slab [64 n][KP i] in regs (4 threads/node) -> swizzled ds_write;
// MFMA accumulates over the chunk's 5 slices; epilogue = fp32 atomicAdd.
// X for L0 = h_in (pad i>=11); else prev agg with folded deg-mean+bias+ReLU+BN.
template <int L0>
__global__ __launch_bounds__(256) void fused_layer(
    const float* __restrict__ Xprev, const float* __restrict__ invdeg,
    const f32x4* __restrict__ bnpPrev,
    const float* __restrict__ ef6, const int* __restrict__ esrc,
    const int* __restrict__ roff,
    const float* __restrict__ W1, const float* __restrict__ b1,
    const unsigned short* __restrict__ Wt,
    float* __restrict__ aggOut) {
  constexpr int KP = L0 ? 32 : 128;
  constexpr int SWZ = L0 ? 3 : 7;
  constexpr int ROWB = KP * 2;
  constexpr int NCHB = 128 * ROWB / 16;  // B-slab 16B chunks
  constexpr int QTR = KP / 4;            // per-thread A elements
  extern __shared__ unsigned short lds[];
  unsigned short* Al = lds;              // [64][KP]   rows = nodes
  unsigned short* Bl = lds + 64 * KP;    // [128][KP]  rows = o
  const int kc = blockIdx.x, mb = blockIdx.y;
  const int t = threadIdx.x;
  // MFMA mapping: 4 waves = 2(m) x 2(n); per wave 2 m-frags x 4 n-frags
  const int w = t >> 6, l = t & 63;
  const int wm = (w >> 1) * 32, wn = (w & 1) * 64;
  const int lr = l & 15, lh = l >> 4;
  // A-build mapping: 4 threads per node
  const int an = t >> 2, ah = t & 3;
  const int node = mb * 64 + an;
  const int start = roff[node], end = roff[node + 1];

  f32x4 acc[2][4] = {};
#pragma unroll
  for (int ks = 0; ks < 5; ++ks) {
    const int k = kc * 5 + ks;
    __syncthreads();  // previous slice's MFMA reads complete before overwrite
    // ---- stage B-slab (pre-swizzled source) ----
    for (int c = t; c < NCHB; c += 256) {
      const int d = c * 16;
      const int o = d / ROWB;
      const int off = d % ROWB;
      gload_lds16((const char*)(Wt + ((size_t)o * NSLICE + k) * KP) +
                      (off ^ ((o & SWZ) << 4)),
                  (char*)Bl + d);
    }
    // ---- build my A quarter-row over this node's edges ----
    float av[QTR];
#pragma unroll
    for (int ii = 0; ii < QTR; ++ii) av[ii] = 0.f;
    float w1r[E_DIMF], b1v = 0.f;
    if (k < 64) {
      b1v = b1[k];
#pragma unroll
      for (int j = 0; j < E_DIMF; ++j) w1r[j] = W1[j * EDGE_H + k];
    }
    for (int idx = start; idx < end; ++idx) {
      const int se = esrc[idx];
      float hv;
      if (k == 64) {
        hv = 1.f;
      } else {
        float a = b1v;
#pragma unroll
        for (int j = 0; j < E_DIMF; ++j) a += ef6[idx * E_DIMF + j] * w1r[j];
        hv = fmaxf(a, 0.f);
      }
      if (L0) {
#pragma unroll
        for (int ii = 0; ii < QTR; ++ii) {
          const int i = ah * QTR + ii;
          const float x = (i < IN_DIM) ? Xprev[se * IN_DIM + i] : 0.f;
          av[ii] += hv * x;
        }
      } else {
        const float idg = invdeg[se];
        const float* ar = Xprev + (size_t)se * HID + ah * QTR;
        const f32x4* bp = bnpPrev + ah * QTR;
#pragma unroll
        for (int ii = 0; ii < QTR; ++ii) {
          const f32x4 b4 = bp[ii];
          const float y = fmaf(ar[ii], idg, b4.x);
          const float x = fmaf(fmaxf(y, 0.f), b4.y, b4.z);
          av[ii] += hv * x;
        }
      }
    }
    // ---- write A quarter to LDS (swizzled), 16B chunks ----
#pragma unroll
    for (int c = 0; c < QTR * 2 / 16; ++c) {
      short8 pk;
#pragma unroll
      for (int u = 0; u < 8; ++u) pk[u] = (short)f2bf(av[c * 8 + u]);
      const int off = ah * (QTR * 2) + c * 16;
      *(short8*)((char*)Al + an * ROWB + (off ^ ((an & SWZ) << 4))) = pk;
    }
    __syncthreads();  // drains vmcnt (B DMA) + lgkmcnt (A writes)
    // ---- MFMA: contract over i (KP wide) ----
#pragma unroll
    for (int kk = 0; kk < KP; kk += 32) {
      short8 a[2], b[4];
      const int kb = (kk + lh * 8) * 2;
#pragma unroll
      for (int mi = 0; mi < 2; ++mi) {
        const int row = wm + mi * 16 + lr;
        a[mi] = *(const short8*)((const char*)Al + row * ROWB +
                                 (kb ^ ((row & SWZ) << 4)));
      }
#pragma unroll
      for (int ni = 0; ni < 4; ++ni) {
        const int col = wn + ni * 16 + lr;
        b[ni] = *(const short8*)((const char*)Bl + col * ROWB +
                                 (kb ^ ((col & SWZ) << 4)));
      }
#pragma unroll
      for (int mi = 0; mi < 2; ++mi)
#pragma unroll
        for (int ni = 0; ni < 4; ++ni)
          acc[mi][ni] = __builtin_amdgcn_mfma_f32_16x16x32_bf16(b[ni], a[mi], acc[mi][ni], 0, 0, 0);
    }
  }
  // ---- epilogue: atomic split-K reduce. D[o][node]: o = wn+ni*16+lh*4+r ----
#pragma unroll
  for (int mi = 0; mi < 2; ++mi) {
    const int nn = mb * 64 + wm + mi * 16 + lr;
    float* ap = aggOut + (size_t)nn * HID;
#pragma unroll
    for (int ni = 0; ni < 4; ++ni) {
#pragma unroll
      for (int r = 0; r < 4; ++r)
        atomicAdd(ap + wn + ni * 16 + lh * 4 + r, acc[mi][ni][r]);
    }
  }
}

// ==== last_bn: finalize layer-3 + readout accumulation ========================
__global__ __launch_bounds__(256) void last_bn(
    const float* __restrict__ agg3, const float* __restrict__ invdeg,
    const f32x4* __restrict__ bnp3, const int* __restrict__ ng,
    float* __restrict__ gsum, unsigned int* __restrict__ gmax,
    float* __restrict__ gcnt) {
  const int idx = blockIdx.x * 256 + threadIdx.x;
  if (idx >= N_NODES * HID) return;
  const int n = idx >> 7, o = idx & 127;
  const f32x4 b4 = bnp3[o];
  const float y = fmaf(agg3[idx], invdeg[n], b4.x);
  const float v = fmaf(fmaxf(y, 0.f), b4.y, b4.z);
  const int g = ng[n];
  atomicAdd(&gsum[g * HID + o], v);
  const unsigned int u = __float_as_uint(v);
  const unsigned int key = (u & 0x80000000u) ? ~u : (u | 0x80000000u);
  atomicMax(&gmax[g * HID + o], key);
  if (o == 0) atomicAdd(&gcnt[g], 1.f);
}

// ---------------- output BN + max decode ----------------
__global__ void out_final(const float* __restrict__ gsum, const unsigned int* __restrict__ gmax,
                          const float* __restrict__ gcnt,
                          const float* __restrict__ g_out, const float* __restrict__ b_out,
                          const float* __restrict__ m_out, const float* __restrict__ v_out,
                          float* __restrict__ out) {
  int g = blockIdx.x, t = threadIdx.x;
  float hn = gsum[g * HID + t] / fmaxf(gcnt[g], 1.0f);
  hn = (hn - m_out[t]) * rsqrtf(v_out[t] + BN_EPS) * g_out[t] + b_out[t];
  unsigned int key = gmax[g * HID + t];
  unsigned int u = (key & 0x80000000u) ? (key ^ 0x80000000u) : ~key;
  out[g * 2 * HID + t] = hn;
  out[g * 2 * HID + HID + t] = __uint_as_float(u);
}

// ================================ host ========================================

extern "C" void kernel_launch(void* const* d_in, const int* in_sizes, int n_in,
                              void* d_out, int out_size, void* d_ws, size_t ws_size,
                              hipStream_t stream) {
  const float* h_in   = (const float*)d_in[0];
  const float* e_in   = (const float*)d_in[1];
  const int*   src    = (const int*)d_in[2];
  const int*   dst    = (const int*)d_in[3];
  const int*   ng     = (const int*)d_in[4];
  const float* eW1_0  = (const float*)d_in[5];
  const float* eb1_0  = (const float*)d_in[6];
  const float* eW2_0  = (const float*)d_in[7];
  const float* eb2_0  = (const float*)d_in[8];
  const float* bias_0 = (const float*)d_in[9];
  const float* gamma_0= (const float*)d_in[10];
  const float* beta_0 = (const float*)d_in[11];
  const float* mean_0 = (const float*)d_in[12];
  const float* var_0  = (const float*)d_in[13];
  const float* eW1    = (const float*)d_in[14];
  const float* eb1    = (const float*)d_in[15];
  const float* eW2    = (const float*)d_in[16];
  const float* eb2    = (const float*)d_in[17];
  const float* biasL  = (const float*)d_in[18];
  const float* gammaL = (const float*)d_in[19];
  const float* betaL  = (const float*)d_in[20];
  const float* meanL  = (const float*)d_in[21];
  const float* varL   = (const float*)d_in[22];
  const float* g_out  = (const float*)d_in[23];
  const float* b_out  = (const float*)d_in[24];
  const float* m_out  = (const float*)d_in[25];
  const float* v_out  = (const float*)d_in[26];
  float* out = (float*)d_out;

  char* ws = (char*)d_ws;
  size_t off = 0;
  auto alloc = [&](size_t bytes) {
    void* pp = ws + off;
    off = (off + bytes + 255) & ~(size_t)255;
    return pp;
  };
  unsigned short* Wt0 = (unsigned short*)alloc((size_t)HID * NSLICE * 32 * 2);
  unsigned short* WtL = (unsigned short*)alloc((size_t)3 * HID * NSLICE * HID * 2);
  float* aggs         = (float*)alloc((size_t)4 * N_NODES * HID * 4);
  float* gsum         = (float*)alloc((size_t)N_GRAPH * HID * 4);
  unsigned int* gmax  = (unsigned int*)alloc((size_t)N_GRAPH * HID * 4);
  float* gcnt         = (float*)alloc((size_t)N_GRAPH * 4);
  int* roff           = (int*)alloc((size_t)(N_NODES + 1) * 4);
  int* cursor         = (int*)alloc((size_t)N_NODES * 4);
  int* esrc           = (int*)alloc((size_t)N_EDGES * 4);
  float* ef6          = (float*)alloc((size_t)N_EDGES * E_DIMF * 4);
  float* invdeg       = (float*)alloc((size_t)N_NODES * 4);
  f32x4* bnp          = (f32x4*)alloc((size_t)4 * HID * 16);

  PrepP P;
  P.eW2_0 = eW2_0; P.eb2_0 = eb2_0; P.eW2 = eW2; P.eb2 = eb2;
  P.dst = dst;
  P.bias_0 = bias_0; P.gamma_0 = gamma_0; P.beta_0 = beta_0;
  P.mean_0 = mean_0; P.var_0 = var_0;
  P.biasL = biasL; P.gammaL = gammaL; P.betaL = betaL;
  P.meanL = meanL; P.varL = varL;
  P.Wt0 = Wt0; P.WtL = WtL;
  P.roff = roff; P.cursor = cursor;
  P.invdeg = invdeg; P.bnp = bnp; P.aggs = aggs;
  P.gsum = gsum; P.gmax = gmax; P.gcnt = gcnt;

  float* agg0 = aggs;
  float* agg1 = aggs + 1 * N_NODES * HID;
  float* agg2 = aggs + 2 * N_NODES * HID;
  float* agg3 = aggs + 3 * N_NODES * HID;

  // node 1: prep (CSR offsets, Wt transposes, agg zero, bnp, invdeg)
  prep_all<<<PREP_BLOCKS, 256, 0, stream>>>(P);
  // node 2: scatter + pre-gather (esrc, ef6)
  scatter_pg<<<N_EDGES / 256, 256, 0, stream>>>(dst, src, e_in, cursor, esrc, ef6);

  // nodes 3-6: the four fused layers
  fused_layer<1><<<dim3(13, 32), 256, (64 + 128) * 32 * 2, stream>>>(
      h_in, invdeg, bnp, ef6, esrc, roff, eW1_0, eb1_0, Wt0, agg0);
  fused_layer<0><<<dim3(13, 32), 256, (64 + 128) * 128 * 2, stream>>>(
      agg0, invdeg, bnp + 0 * HID, ef6, esrc, roff,
      eW1 + 0 * E_DIMF * EDGE_H, eb1 + 0 * EDGE_H,
      WtL + (size_t)0 * HID * NSLICE * HID, agg1);
  fused_layer<0><<<dim3(13, 32), 256, (64 + 128) * 128 * 2, stream>>>(
      agg1, invdeg, bnp + 1 * HID, ef6, esrc, roff,
      eW1 + 1 * E_DIMF * EDGE_H, eb1 + 1 * EDGE_H,
      WtL + (size_t)1 * HID * NSLICE * HID, agg2);
  fused_layer<0><<<dim3(13, 32), 256, (64 + 128) * 128 * 2, stream>>>(
      agg2, invdeg, bnp + 2 * HID, ef6, esrc, roff,
      eW1 + 2 * E_DIMF * EDGE_H, eb1 + 2 * EDGE_H,
      WtL + (size_t)2 * HID * NSLICE * HID, agg3);

  // node 7: finalize layer 3 + readout accumulation
  last_bn<<<N_NODES * HID / 256, 256, 0, stream>>>(agg3, invdeg, bnp + 3 * HID,
                                                   ng, gsum, gmax, gcnt);
  // node 8: output BN + max decode
  out_final<<<N_GRAPH, HID, 0, stream>>>(gsum, gmax, gcnt, g_out, b_out, m_out,
                                         v_out, out);
}

// Round 13
// 178.858 us; speedup vs baseline: 2.8080x; 2.8080x over previous
//
#include <hip/hip_runtime.h>
#include <stdint.h>

#define N_NODES 2048
#define N_EDGES 4096
#define N_GRAPH 16
#define IN_DIM  11
#define HID     128
#define E_DIMF  6
#define EDGE_H  64
#define NSLICE  65            // 64 h-slices + 1 bias slice
#define ZCOLS   (NSLICE*HID)  // 8320
#define BN_EPS  1e-5f

typedef __attribute__((ext_vector_type(8))) short short8;
typedef __attribute__((ext_vector_type(4))) float f32x4;

static __device__ __forceinline__ float bf2f(unsigned short u) {
  union { float f; uint32_t i; } x; x.i = ((uint32_t)u) << 16; return x.f;
}
static __device__ __forceinline__ unsigned short f2bf(float f) {
  union { float f; uint32_t i; } x; x.f = f;
  uint32_t i = x.i;
  return (unsigned short)((i + 0x7FFFu + ((i >> 16) & 1u)) >> 16);
}

// direct global->LDS DMA, 16B per lane. LDS dest must be base+lane*16 (linear).
static __device__ __forceinline__ void gload_lds16(const void* g, void* l) {
  __builtin_amdgcn_global_load_lds(
      (const __attribute__((address_space(1))) uint32_t*)g,
      (__attribute__((address_space(3))) uint32_t*)l, 16, 0, 0);
}

struct PrepP {
  const float *eW2_0, *eb2_0, *eW2, *eb2, *h_in;
  const int *dst;
  unsigned short *WbT0, *WbTL, *xb0;
  int *roff, *cursor;
  float *gsum;
  unsigned int *gmax;
  float *gcnt;
};

// ==== prep_all: CSR hist+scan(block 0) + transposes + xb0 + zero (R11) ========
#define PREP_BLOCKS 270
__global__ __launch_bounds__(256) void prep_all(PrepP p) {
  const int bid = blockIdx.x, t = threadIdx.x;
  __shared__ union {
    struct { int hist[N_NODES]; int part[256]; } csr;       // 9 KB
    unsigned short tile[128 * 130];                          // 33.3 KB
  } sm;

  if (bid == 0) {
    // ---- deg histogram + exclusive scan -> roff, global cursor ----
    for (int i = t; i < N_NODES; i += 256) sm.csr.hist[i] = 0;
    __syncthreads();
    for (int e = t; e < N_EDGES; e += 256) atomicAdd(&sm.csr.hist[p.dst[e]], 1);
    __syncthreads();
    const int base = t * 8;
    int loc[8];
    int s = 0;
#pragma unroll
    for (int j = 0; j < 8; ++j) { loc[j] = s; s += sm.csr.hist[base + j]; }
    sm.csr.part[t] = s;
    __syncthreads();
    for (int d = 1; d < 256; d <<= 1) {  // Hillis-Steele inclusive scan
      int v = sm.csr.part[t];
      if (t >= d) v += sm.csr.part[t - d];
      __syncthreads();
      sm.csr.part[t] = v;
      __syncthreads();
    }
    const int pre = (t == 0) ? 0 : sm.csr.part[t - 1];
#pragma unroll
    for (int j = 0; j < 8; ++j) {
      p.roff[base + j] = pre + loc[j];
      p.cursor[base + j] = pre + loc[j];
    }
    if (t == 255) p.roff[N_NODES] = pre + s;
  } else if (bid <= 260) {
    // ---- transpose one W2 slab -> WbT [(k,o)][i] bf16 ----
    const int s = bid - 1;
    if (s < 65) {  // layer 0, KP=32, din=11
      const int k = s;
      const float* srcp = (k < 64) ? (p.eW2_0 + (size_t)k * IN_DIM * HID) : p.eb2_0;
      for (int j = t; j < IN_DIM * HID; j += 256) {
        int i = j >> 7, o = j & 127;
        sm.tile[i * 130 + o] = f2bf(srcp[j]);
      }
      __syncthreads();
      for (int j = t; j < HID * 32; j += 256) {
        int o = j >> 5, i = j & 31;
        p.WbT0[((size_t)k * HID + o) * 32 + i] =
            (i < IN_DIM) ? sm.tile[i * 130 + o] : (unsigned short)0;
      }
    } else {  // layers 1..3, KP=128
      const int sl = s - 65, l = sl / 65, k = sl % 65;
      const float* srcp = (k < 64) ? (p.eW2 + ((size_t)l * 64 + k) * (HID * HID))
                                   : (p.eb2 + (size_t)l * (HID * HID));
      unsigned short* dstp = p.WbTL + (size_t)l * ZCOLS * HID;
      for (int j = t; j < HID * HID; j += 256) {
        int i = j >> 7, o = j & 127;
        sm.tile[i * 130 + o] = f2bf(srcp[j]);
      }
      __syncthreads();
      for (int j = t; j < HID * HID; j += 256) {
        int o = j >> 7, i = j & 127;
        dstp[((size_t)k * HID + o) * HID + i] = sm.tile[i * 130 + o];
      }
    }
  } else if (bid <= 268) {
    // ---- layer-0 input cast -> bf16 padded [N][32] ----
    for (int idx = (bid - 261) * 256 + t; idx < N_NODES * 32; idx += 8 * 256) {
      int n = idx >> 5, i = idx & 31;
      p.xb0[idx] = f2bf(i < IN_DIM ? p.h_in[n * IN_DIM + i] : 0.f);
    }
  } else {
    // ---- zero accumulators ----
    for (int i = t; i < N_GRAPH * HID; i += 256) {
      p.gsum[i] = 0.f;
      p.gmax[i] = 0u;
    }
    if (t < N_GRAPH) p.gcnt[t] = 0.f;
  }
}

// ---------------- Z GEMM (R11 body) + optional fused scatter row --------------
// SCAT: grid.y==16 blocks perform the edge scatter + esrc/ef6 pre-gather
// (independent work at the same dependency frontier -> one fewer graph node).
template <int KP, int SWZ, int SCAT>
__global__ __launch_bounds__(256) void gemm_z(
    const unsigned short* __restrict__ Xb, const unsigned short* __restrict__ WbT,
    unsigned short* __restrict__ Z,
    const int* __restrict__ dst, const int* __restrict__ srcv,
    const float* __restrict__ efeat, int* __restrict__ cursor,
    int* __restrict__ esrc, float* __restrict__ ef6) {
  if (SCAT && blockIdx.y == 16) {
    const int e = blockIdx.x * 256 + threadIdx.x;
    if (e < N_EDGES) {
      float ef[E_DIMF];
#pragma unroll
      for (int j = 0; j < E_DIMF; ++j) ef[j] = efeat[e * E_DIMF + j];
      const int se = srcv[e];
      const int pos = atomicAdd(&cursor[dst[e]], 1);
      esrc[pos] = se;
#pragma unroll
      for (int j = 0; j < E_DIMF; ++j) ef6[pos * E_DIMF + j] = ef[j];
    }
    return;
  }
  extern __shared__ unsigned short lds[];
  unsigned short* Al = lds;
  unsigned short* Bl = lds + 128 * KP;
  const int nb = blockIdx.x;
  const int mb = blockIdx.y;
  const int t = threadIdx.x;
  const int ROWB = KP * 2;
  const int NCH = 128 * ROWB / 16;
  const unsigned short* Asrc = Xb + (size_t)mb * 128 * KP;
  const unsigned short* Bsrc = WbT + (size_t)nb * 128 * KP;
  for (int c = t; c < NCH; c += 256) {
    const int d = c * 16;                 // linear LDS dest (lane-consecutive)
    const int row = d / ROWB;
    const int s = d ^ ((row & SWZ) << 4); // inverse-swizzled global source
    gload_lds16((const char*)Asrc + s, (char*)Al + d);
    gload_lds16((const char*)Bsrc + s, (char*)Bl + d);
  }
  __syncthreads();
  const int w = t >> 6, l = t & 63;
  const int wm = (w >> 1) * 64, wn = (w & 1) * 64;
  const int lr = l & 15, lh = l >> 4;
  f32x4 acc[4][4] = {};
#pragma unroll
  for (int kk = 0; kk < KP; kk += 32) {
    short8 a[4], b[4];
    const int kb = (kk + lh * 8) * 2;
#pragma unroll
    for (int mi = 0; mi < 4; ++mi) {
      int row = wm + mi * 16 + lr;
      int addr = row * ROWB + (kb ^ ((row & SWZ) << 4));
      a[mi] = *(const short8*)((const char*)Al + addr);
    }
#pragma unroll
    for (int ni = 0; ni < 4; ++ni) {
      int col = wn + ni * 16 + lr;
      int addr = col * ROWB + (kb ^ ((col & SWZ) << 4));
      b[ni] = *(const short8*)((const char*)Bl + addr);
    }
#pragma unroll
    for (int mi = 0; mi < 4; ++mi)
#pragma unroll
      for (int ni = 0; ni < 4; ++ni)
        acc[mi][ni] = __builtin_amdgcn_mfma_f32_16x16x32_bf16(b[ni], a[mi], acc[mi][ni], 0, 0, 0);
  }
#pragma unroll
  for (int mi = 0; mi < 4; ++mi) {
    const int node = mb * 128 + wm + mi * 16 + lr;
    unsigned short* zp = Z + (size_t)node * ZCOLS + nb * 128 + wn + lh * 4;
#pragma unroll
    for (int ni = 0; ni < 4; ++ni) {
      ushort4 pk;
      pk.x = f2bf(acc[mi][ni][0]);
      pk.y = f2bf(acc[mi][ni][1]);
      pk.z = f2bf(acc[mi][ni][2]);
      pk.w = f2bf(acc[mi][ni][3]);
      *(ushort4*)(zp + ni * 16) = pk;
    }
  }
}

// ------- per-node gather (R11) + edge-loop software pipelining ----------------
// 256 threads = 2 nodes: hh=t>>7; per node: cg2 = tt&15 (8 channels),
// kg = tt>>4 (8 k). W1/b1 hoisted; esrc/ef6 of edge i+1 prefetched during
// edge i's compute (load reorder only -> identical numerics).
template <int LAST>
__global__ __launch_bounds__(256) void node_gather(
    const float* __restrict__ ef6, const float* __restrict__ W1,
    const float* __restrict__ b1, const unsigned short* __restrict__ Z,
    const int* __restrict__ esrc, const int* __restrict__ roff,
    const float* __restrict__ bias, const float* __restrict__ gamma,
    const float* __restrict__ beta, const float* __restrict__ mean,
    const float* __restrict__ var,
    unsigned short* __restrict__ xbout,
    const int* __restrict__ ng, float* __restrict__ gsum,
    unsigned int* __restrict__ gmax, float* __restrict__ gcnt) {
  const int t = threadIdx.x;
  const int hh = t >> 7, tt = t & 127;
  const int n = blockIdx.x * 2 + hh;
  const int cg2 = tt & 15, kg = tt >> 4;
  const int start = roff[n], end = roff[n + 1];
  __shared__ float red[2][128][9];

  // hoist this thread's W1 column block + b1 into registers (edge-invariant)
  float w1r[E_DIMF][8], b1r[8];
#pragma unroll
  for (int kk = 0; kk < 8; ++kk) {
    const int k = kg * 8 + kk;
    b1r[kk] = b1[k];
#pragma unroll
    for (int j = 0; j < E_DIMF; ++j) w1r[j][kk] = W1[j * EDGE_H + k];
  }

  float acc8[8] = {};
  int se_nx = 0;
  float ef_nx[E_DIMF];
  if (start < end) {
    se_nx = esrc[start];
#pragma unroll
    for (int j = 0; j < E_DIMF; ++j) ef_nx[j] = ef6[start * E_DIMF + j];
  }
  for (int idx = start; idx < end; ++idx) {
    const int se = se_nx;
    float ef[E_DIMF];
#pragma unroll
    for (int j = 0; j < E_DIMF; ++j) ef[j] = ef_nx[j];
    if (idx + 1 < end) {  // prefetch next edge while this one computes
      se_nx = esrc[idx + 1];
#pragma unroll
      for (int j = 0; j < E_DIMF; ++j) ef_nx[j] = ef6[(idx + 1) * E_DIMF + j];
    }
    float hk[8];
#pragma unroll
    for (int kk = 0; kk < 8; ++kk) {
      float a = b1r[kk];
#pragma unroll
      for (int j = 0; j < E_DIMF; ++j) a += ef[j] * w1r[j][kk];
      hk[kk] = fmaxf(a, 0.f);
    }
    const unsigned short* zr = Z + (size_t)se * ZCOLS + cg2 * 8;
#pragma unroll
    for (int kk = 0; kk < 8; ++kk) {
      short8 v = *(const short8*)(zr + (kg * 8 + kk) * HID);
      const float hv = hk[kk];
#pragma unroll
      for (int j = 0; j < 8; ++j) acc8[j] += hv * bf2f((unsigned short)v[j]);
    }
    if (kg == 0) {  // bias slice k=64, h=1
      short8 v = *(const short8*)(zr + 64 * HID);
#pragma unroll
      for (int j = 0; j < 8; ++j) acc8[j] += bf2f((unsigned short)v[j]);
    }
  }
#pragma unroll
  for (int j = 0; j < 8; ++j) red[hh][tt][j] = acc8[j];
  __syncthreads();
  const int o = tt;
  float s = 0.f;
#pragma unroll
  for (int k2 = 0; k2 < 8; ++k2) s += red[hh][k2 * 16 + (o >> 3)][o & 7];
  const int dg = end - start;
  float v = s / (float)(dg > 0 ? dg : 1) + bias[o];
  v = fmaxf(v, 0.f);
  v = (v - mean[o]) * rsqrtf(var[o] + BN_EPS) * gamma[o] + beta[o];
  if (!LAST) {
    xbout[n * HID + o] = f2bf(v);
  } else {
    const int g = ng[n];
    atomicAdd(&gsum[g * HID + o], v);
    unsigned int u = __float_as_uint(v);
    unsigned int key = (u & 0x80000000u) ? ~u : (u | 0x80000000u);
    atomicMax(&gmax[g * HID + o], key);
    if (o == 0) atomicAdd(&gcnt[g], 1.f);
  }
}

// ---------------- output BN + max decode ----------------
__global__ void out_final(const float* __restrict__ gsum, const unsigned int* __restrict__ gmax,
                          const float* __restrict__ gcnt,
                          const float* __restrict__ g_out, const float* __restrict__ b_out,
                          const float* __restrict__ m_out, const float* __restrict__ v_out,
                          float* __restrict__ out) {
  int g = blockIdx.x, t = threadIdx.x;
  float hn = gsum[g * HID + t] / fmaxf(gcnt[g], 1.0f);
  hn = (hn - m_out[t]) * rsqrtf(v_out[t] + BN_EPS) * g_out[t] + b_out[t];
  unsigned int key = gmax[g * HID + t];
  unsigned int u = (key & 0x80000000u) ? (key ^ 0x80000000u) : ~key;
  out[g * 2 * HID + t] = hn;
  out[g * 2 * HID + HID + t] = __uint_as_float(u);
}

// ================================ host ========================================

extern "C" void kernel_launch(void* const* d_in, const int* in_sizes, int n_in,
                              void* d_out, int out_size, void* d_ws, size_t ws_size,
                              hipStream_t stream) {
  const float* h_in   = (const float*)d_in[0];
  const float* e_in   = (const float*)d_in[1];
  const int*   src    = (const int*)d_in[2];
  const int*   dst    = (const int*)d_in[3];
  const int*   ng     = (const int*)d_in[4];
  const float* eW1_0  = (const float*)d_in[5];
  const float* eb1_0  = (const float*)d_in[6];
  const float* eW2_0  = (const float*)d_in[7];
  const float* eb2_0  = (const float*)d_in[8];
  const float* bias_0 = (const float*)d_in[9];
  const float* gamma_0= (const float*)d_in[10];
  const float* beta_0 = (const float*)d_in[11];
  const float* mean_0 = (const float*)d_in[12];
  const float* var_0  = (const float*)d_in[13];
  const float* eW1    = (const float*)d_in[14];
  const float* eb1    = (const float*)d_in[15];
  const float* eW2    = (const float*)d_in[16];
  const float* eb2    = (const float*)d_in[17];
  const float* biasL  = (const float*)d_in[18];
  const float* gammaL = (const float*)d_in[19];
  const float* betaL  = (const float*)d_in[20];
  const float* meanL  = (const float*)d_in[21];
  const float* varL   = (const float*)d_in[22];
  const float* g_out  = (const float*)d_in[23];
  const float* b_out  = (const float*)d_in[24];
  const float* m_out  = (const float*)d_in[25];
  const float* v_out  = (const float*)d_in[26];
  float* out = (float*)d_out;

  char* ws = (char*)d_ws;
  size_t off = 0;
  auto alloc = [&](size_t bytes) {
    void* pp = ws + off;
    off = (off + bytes + 255) & ~(size_t)255;
    return pp;
  };
  unsigned short* Z    = (unsigned short*)alloc((size_t)N_NODES * ZCOLS * 2);
  unsigned short* WbT0 = (unsigned short*)alloc((size_t)ZCOLS * 32 * 2);
  unsigned short* WbTL = (unsigned short*)alloc((size_t)3 * ZCOLS * HID * 2);
  unsigned short* xb0  = (unsigned short*)alloc((size_t)N_NODES * 32 * 2);
  unsigned short* xb   = (unsigned short*)alloc((size_t)N_NODES * HID * 2);
  float* gsum          = (float*)alloc((size_t)N_GRAPH * HID * 4);
  unsigned int* gmax   = (unsigned int*)alloc((size_t)N_GRAPH * HID * 4);
  float* gcnt          = (float*)alloc((size_t)N_GRAPH * 4);
  int* roff            = (int*)alloc((size_t)(N_NODES + 1) * 4);
  int* cursor          = (int*)alloc((size_t)N_NODES * 4);
  int* esrc            = (int*)alloc((size_t)N_EDGES * 4);
  float* ef6           = (float*)alloc((size_t)N_EDGES * E_DIMF * 4);

  PrepP P;
  P.eW2_0 = eW2_0; P.eb2_0 = eb2_0; P.eW2 = eW2; P.eb2 = eb2; P.h_in = h_in;
  P.dst = dst;
  P.WbT0 = WbT0; P.WbTL = WbTL; P.xb0 = xb0;
  P.roff = roff; P.cursor = cursor;
  P.gsum = gsum; P.gmax = gmax; P.gcnt = gcnt;

  // node 1: prep (CSR offsets, transposes, xb0, zero)
  prep_all<<<PREP_BLOCKS, 256, 0, stream>>>(P);

  // node 2: layer-0 gemm + fused scatter/pre-gather (grid.y==16 row)
  gemm_z<32, 3, 1><<<dim3(65, 17), 256, 2 * 128 * 32 * 2, stream>>>(
      xb0, WbT0, Z, dst, src, e_in, cursor, esrc, ef6);
  // node 3: layer-0 gather
  node_gather<0><<<N_NODES / 2, 256, 0, stream>>>(ef6, eW1_0, eb1_0, Z, esrc, roff,
                                                  bias_0, gamma_0, beta_0, mean_0,
                                                  var_0, xb, ng, gsum, gmax, gcnt);

  // nodes 4-9: layers 1..3
  for (int l = 0; l < 3; ++l) {
    gemm_z<128, 7, 0><<<dim3(65, 16), 256, 2 * 128 * 128 * 2, stream>>>(
        xb, WbTL + (size_t)l * ZCOLS * HID, Z, nullptr, nullptr, nullptr,
        nullptr, nullptr, nullptr);
    if (l < 2)
      node_gather<0><<<N_NODES / 2, 256, 0, stream>>>(
          ef6, eW1 + l * E_DIMF * EDGE_H, eb1 + l * EDGE_H, Z, esrc, roff,
          biasL + l * HID, gammaL + l * HID, betaL + l * HID, meanL + l * HID,
          varL + l * HID, xb, ng, gsum, gmax, gcnt);
    else
      node_gather<1><<<N_NODES / 2, 256, 0, stream>>>(
          ef6, eW1 + l * E_DIMF * EDGE_H, eb1 + l * EDGE_H, Z, esrc, roff,
          biasL + l * HID, gammaL + l * HID, betaL + l * HID, meanL + l * HID,
          varL + l * HID, xb, ng, gsum, gmax, gcnt);
  }

  // node 10: readout finale
  out_final<<<N_GRAPH, HID, 0, stream>>>(gsum, gmax, gcnt, g_out, b_out, m_out,
                                         v_out, out);
}

// Round 14
// 172.305 us; speedup vs baseline: 2.9148x; 1.0380x over previous
//
#include <hip/hip_runtime.h>
#include <stdint.h>

#define N_NODES 2048
#define N_EDGES 4096
#define N_GRAPH 16
#define IN_DIM  11
#define HID     128
#define E_DIMF  6
#define EDGE_H  64
#define NSLICE  65            // 64 h-slices + 1 bias slice
#define ZCOLS   (NSLICE*HID)  // 8320
#define BN_EPS  1e-5f

typedef __attribute__((ext_vector_type(8))) short short8;
typedef __attribute__((ext_vector_type(4))) float f32x4;

static __device__ __forceinline__ float bf2f(unsigned short u) {
  union { float f; uint32_t i; } x; x.i = ((uint32_t)u) << 16; return x.f;
}
static __device__ __forceinline__ unsigned short f2bf(float f) {
  union { float f; uint32_t i; } x; x.f = f;
  uint32_t i = x.i;
  return (unsigned short)((i + 0x7FFFu + ((i >> 16) & 1u)) >> 16);
}

// direct global->LDS DMA, 16B per lane. LDS dest must be base+lane*16 (linear).
static __device__ __forceinline__ void gload_lds16(const void* g, void* l) {
  __builtin_amdgcn_global_load_lds(
      (const __attribute__((address_space(1))) uint32_t*)g,
      (__attribute__((address_space(3))) uint32_t*)l, 16, 0, 0);
}

struct PrepP {
  const float *eW2_0, *eb2_0, *eW2, *eb2, *h_in;
  const int *dst;
  unsigned short *WbT0, *WbTL, *xb0;
  int *roff, *cursor, *nodeorder;
  float *gsum;
  unsigned int *gmax;
  float *gcnt;
};

// ==== prep_all: CSR+degsort(block 0) + vectorized transposes + xb0 + zero =====
#define PREP_BLOCKS 270
__global__ __launch_bounds__(256) void prep_all(PrepP p) {
  const int bid = blockIdx.x, t = threadIdx.x;
  __shared__ union {
    struct { int hist[N_NODES]; int part[256]; } csr;       // 9 KB
    unsigned short tile[128 * 130];                          // 33.3 KB
  } sm;

  if (bid == 0) {
    // ---- deg histogram + exclusive scan -> roff, cursor ----
    for (int i = t; i < N_NODES; i += 256) sm.csr.hist[i] = 0;
    __syncthreads();
    for (int e = t; e < N_EDGES; e += 256) atomicAdd(&sm.csr.hist[p.dst[e]], 1);
    __syncthreads();
    const int base = t * 8;
    int loc[8];
    int s = 0;
#pragma unroll
    for (int j = 0; j < 8; ++j) { loc[j] = s; s += sm.csr.hist[base + j]; }
    sm.csr.part[t] = s;
    __syncthreads();
    for (int d = 1; d < 256; d <<= 1) {  // Hillis-Steele inclusive scan
      int v = sm.csr.part[t];
      if (t >= d) v += sm.csr.part[t - d];
      __syncthreads();
      sm.csr.part[t] = v;
      __syncthreads();
    }
    const int pre = (t == 0) ? 0 : sm.csr.part[t - 1];
#pragma unroll
    for (int j = 0; j < 8; ++j) {
      p.roff[base + j] = pre + loc[j];
      p.cursor[base + j] = pre + loc[j];
    }
    if (t == 255) p.roff[N_NODES] = pre + s;
    __syncthreads();
    // ---- degree counting sort -> nodeorder (balanced gather blocks) ----
    // hist[] still holds per-node deg; reuse part[0..31] as bucket counters.
    if (t < 32) sm.csr.part[t] = 0;
    __syncthreads();
    for (int i = t; i < N_NODES; i += 256)
      atomicAdd(&sm.csr.part[min(sm.csr.hist[i], 31)], 1);
    __syncthreads();
    if (t == 0) {
      int run = 0;
#pragma unroll
      for (int b = 0; b < 32; ++b) { int c = sm.csr.part[b]; sm.csr.part[b] = run; run += c; }
    }
    __syncthreads();
    for (int i = t; i < N_NODES; i += 256) {
      int pos = atomicAdd(&sm.csr.part[min(sm.csr.hist[i], 31)], 1);
      p.nodeorder[pos] = i;
    }
  } else if (bid <= 260) {
    // ---- transpose one W2 slab -> WbT [(k,o)][i] bf16 (vectorized) ----
    const int s = bid - 1;
    if (s < 65) {  // layer 0, KP=32, din=11
      const int k = s;
      const float* srcp = (k < 64) ? (p.eW2_0 + (size_t)k * IN_DIM * HID) : p.eb2_0;
      for (int j4 = t; j4 < IN_DIM * HID / 4; j4 += 256) {   // float4 reads
        const float4 v = *(const float4*)(srcp + j4 * 4);
        const int i = j4 >> 5, o = (j4 & 31) * 4;
        sm.tile[i * 130 + o + 0] = f2bf(v.x);
        sm.tile[i * 130 + o + 1] = f2bf(v.y);
        sm.tile[i * 130 + o + 2] = f2bf(v.z);
        sm.tile[i * 130 + o + 3] = f2bf(v.w);
      }
      __syncthreads();
      for (int c = t; c < HID * 32 / 8; c += 256) {          // short8 writes
        const int o = c >> 2, i0 = (c & 3) * 8;
        short8 pk;
#pragma unroll
        for (int u = 0; u < 8; ++u)
          pk[u] = (i0 + u < IN_DIM) ? (short)sm.tile[(i0 + u) * 130 + o] : (short)0;
        *(short8*)(p.WbT0 + ((size_t)k * HID + o) * 32 + i0) = pk;
      }
    } else {  // layers 1..3, KP=128
      const int sl = s - 65, l = sl / 65, k = sl % 65;
      const float* srcp = (k < 64) ? (p.eW2 + ((size_t)l * 64 + k) * (HID * HID))
                                   : (p.eb2 + (size_t)l * (HID * HID));
      unsigned short* dstp = p.WbTL + (size_t)l * ZCOLS * HID;
      for (int j4 = t; j4 < HID * HID / 4; j4 += 256) {      // float4 reads
        const float4 v = *(const float4*)(srcp + j4 * 4);
        const int i = j4 >> 5, o = (j4 & 31) * 4;
        sm.tile[i * 130 + o + 0] = f2bf(v.x);
        sm.tile[i * 130 + o + 1] = f2bf(v.y);
        sm.tile[i * 130 + o + 2] = f2bf(v.z);
        sm.tile[i * 130 + o + 3] = f2bf(v.w);
      }
      __syncthreads();
      for (int c = t; c < HID * HID / 8; c += 256) {         // short8 writes
        const int o = c >> 4, i0 = (c & 15) * 8;
        short8 pk;
#pragma unroll
        for (int u = 0; u < 8; ++u) pk[u] = (short)sm.tile[(i0 + u) * 130 + o];
        *(short8*)(dstp + ((size_t)k * HID + o) * HID + i0) = pk;
      }
    }
  } else if (bid <= 268) {
    // ---- layer-0 input cast -> bf16 padded [N][32] ----
    for (int idx = (bid - 261) * 256 + t; idx < N_NODES * 32; idx += 8 * 256) {
      int n = idx >> 5, i = idx & 31;
      p.xb0[idx] = f2bf(i < IN_DIM ? p.h_in[n * IN_DIM + i] : 0.f);
    }
  } else {
    // ---- zero accumulators ----
    for (int i = t; i < N_GRAPH * HID; i += 256) {
      p.gsum[i] = 0.f;
      p.gmax[i] = 0u;
    }
    if (t < N_GRAPH) p.gcnt[t] = 0.f;
  }
}

// ---------------- Z GEMM (R11 body) + fused scatter row ----------------------
template <int KP, int SWZ, int SCAT>
__global__ __launch_bounds__(256) void gemm_z(
    const unsigned short* __restrict__ Xb, const unsigned short* __restrict__ WbT,
    unsigned short* __restrict__ Z,
    const int* __restrict__ dst, const int* __restrict__ srcv,
    const float* __restrict__ efeat, int* __restrict__ cursor,
    int* __restrict__ esrc, float* __restrict__ ef6) {
  if (SCAT && blockIdx.y == 16) {
    const int e = blockIdx.x * 256 + threadIdx.x;
    if (e < N_EDGES) {
      float ef[E_DIMF];
#pragma unroll
      for (int j = 0; j < E_DIMF; ++j) ef[j] = efeat[e * E_DIMF + j];
      const int se = srcv[e];
      const int pos = atomicAdd(&cursor[dst[e]], 1);
      esrc[pos] = se;
#pragma unroll
      for (int j = 0; j < E_DIMF; ++j) ef6[pos * E_DIMF + j] = ef[j];
    }
    return;
  }
  extern __shared__ unsigned short lds[];
  unsigned short* Al = lds;
  unsigned short* Bl = lds + 128 * KP;
  const int nb = blockIdx.x;
  const int mb = blockIdx.y;
  const int t = threadIdx.x;
  const int ROWB = KP * 2;
  const int NCH = 128 * ROWB / 16;
  const unsigned short* Asrc = Xb + (size_t)mb * 128 * KP;
  const unsigned short* Bsrc = WbT + (size_t)nb * 128 * KP;
  for (int c = t; c < NCH; c += 256) {
    const int d = c * 16;                 // linear LDS dest (lane-consecutive)
    const int row = d / ROWB;
    const int s = d ^ ((row & SWZ) << 4); // inverse-swizzled global source
    gload_lds16((const char*)Asrc + s, (char*)Al + d);
    gload_lds16((const char*)Bsrc + s, (char*)Bl + d);
  }
  __syncthreads();
  const int w = t >> 6, l = t & 63;
  const int wm = (w >> 1) * 64, wn = (w & 1) * 64;
  const int lr = l & 15, lh = l >> 4;
  f32x4 acc[4][4] = {};
#pragma unroll
  for (int kk = 0; kk < KP; kk += 32) {
    short8 a[4], b[4];
    const int kb = (kk + lh * 8) * 2;
#pragma unroll
    for (int mi = 0; mi < 4; ++mi) {
      int row = wm + mi * 16 + lr;
      int addr = row * ROWB + (kb ^ ((row & SWZ) << 4));
      a[mi] = *(const short8*)((const char*)Al + addr);
    }
#pragma unroll
    for (int ni = 0; ni < 4; ++ni) {
      int col = wn + ni * 16 + lr;
      int addr = col * ROWB + (kb ^ ((col & SWZ) << 4));
      b[ni] = *(const short8*)((const char*)Bl + addr);
    }
#pragma unroll
    for (int mi = 0; mi < 4; ++mi)
#pragma unroll
      for (int ni = 0; ni < 4; ++ni)
        acc[mi][ni] = __builtin_amdgcn_mfma_f32_16x16x32_bf16(b[ni], a[mi], acc[mi][ni], 0, 0, 0);
  }
#pragma unroll
  for (int mi = 0; mi < 4; ++mi) {
    const int node = mb * 128 + wm + mi * 16 + lr;
    unsigned short* zp = Z + (size_t)node * ZCOLS + nb * 128 + wn + lh * 4;
#pragma unroll
    for (int ni = 0; ni < 4; ++ni) {
      ushort4 pk;
      pk.x = f2bf(acc[mi][ni][0]);
      pk.y = f2bf(acc[mi][ni][1]);
      pk.z = f2bf(acc[mi][ni][2]);
      pk.w = f2bf(acc[mi][ni][3]);
      *(ushort4*)(zp + ni * 16) = pk;
    }
  }
}

// ------- per-node gather (R13 body) + degree-balanced node assignment ---------
template <int LAST>
__global__ __launch_bounds__(256) void node_gather(
    const float* __restrict__ ef6, const float* __restrict__ W1,
    const float* __restrict__ b1, const unsigned short* __restrict__ Z,
    const int* __restrict__ esrc, const int* __restrict__ roff,
    const int* __restrict__ nodeorder,
    const float* __restrict__ bias, const float* __restrict__ gamma,
    const float* __restrict__ beta, const float* __restrict__ mean,
    const float* __restrict__ var,
    unsigned short* __restrict__ xbout,
    const int* __restrict__ ng, float* __restrict__ gsum,
    unsigned int* __restrict__ gmax, float* __restrict__ gcnt) {
  const int t = threadIdx.x;
  const int hh = t >> 7, tt = t & 127;
  const int n = nodeorder[blockIdx.x * 2 + hh];  // deg-sorted: paired nodes balanced
  const int cg2 = tt & 15, kg = tt >> 4;
  const int start = roff[n], end = roff[n + 1];
  __shared__ float red[2][128][9];

  // hoist this thread's W1 column block + b1 into registers (edge-invariant)
  float w1r[E_DIMF][8], b1r[8];
#pragma unroll
  for (int kk = 0; kk < 8; ++kk) {
    const int k = kg * 8 + kk;
    b1r[kk] = b1[k];
#pragma unroll
    for (int j = 0; j < E_DIMF; ++j) w1r[j][kk] = W1[j * EDGE_H + k];
  }

  float acc8[8] = {};
  int se_nx = 0;
  float ef_nx[E_DIMF];
  if (start < end) {
    se_nx = esrc[start];
#pragma unroll
    for (int j = 0; j < E_DIMF; ++j) ef_nx[j] = ef6[start * E_DIMF + j];
  }
  for (int idx = start; idx < end; ++idx) {
    const int se = se_nx;
    float ef[E_DIMF];
#pragma unroll
    for (int j = 0; j < E_DIMF; ++j) ef[j] = ef_nx[j];
    if (idx + 1 < end) {  // prefetch next edge while this one computes
      se_nx = esrc[idx + 1];
#pragma unroll
      for (int j = 0; j < E_DIMF; ++j) ef_nx[j] = ef6[(idx + 1) * E_DIMF + j];
    }
    float hk[8];
#pragma unroll
    for (int kk = 0; kk < 8; ++kk) {
      float a = b1r[kk];
#pragma unroll
      for (int j = 0; j < E_DIMF; ++j) a += ef[j] * w1r[j][kk];
      hk[kk] = fmaxf(a, 0.f);
    }
    const unsigned short* zr = Z + (size_t)se * ZCOLS + cg2 * 8;
#pragma unroll
    for (int kk = 0; kk < 8; ++kk) {
      short8 v = *(const short8*)(zr + (kg * 8 + kk) * HID);
      const float hv = hk[kk];
#pragma unroll
      for (int j = 0; j < 8; ++j) acc8[j] += hv * bf2f((unsigned short)v[j]);
    }
    if (kg == 0) {  // bias slice k=64, h=1
      short8 v = *(const short8*)(zr + 64 * HID);
#pragma unroll
      for (int j = 0; j < 8; ++j) acc8[j] += bf2f((unsigned short)v[j]);
    }
  }
#pragma unroll
  for (int j = 0; j < 8; ++j) red[hh][tt][j] = acc8[j];
  __syncthreads();
  const int o = tt;
  float s = 0.f;
#pragma unroll
  for (int k2 = 0; k2 < 8; ++k2) s += red[hh][k2 * 16 + (o >> 3)][o & 7];
  const int dg = end - start;
  float v = s / (float)(dg > 0 ? dg : 1) + bias[o];
  v = fmaxf(v, 0.f);
  v = (v - mean[o]) * rsqrtf(var[o] + BN_EPS) * gamma[o] + beta[o];
  if (!LAST) {
    xbout[n * HID + o] = f2bf(v);
  } else {
    const int g = ng[n];
    atomicAdd(&gsum[g * HID + o], v);
    unsigned int u = __float_as_uint(v);
    unsigned int key = (u & 0x80000000u) ? ~u : (u | 0x80000000u);
    atomicMax(&gmax[g * HID + o], key);
    if (o == 0) atomicAdd(&gcnt[g], 1.f);
  }
}

// ---------------- output BN + max decode ----------------
__global__ void out_final(const float* __restrict__ gsum, const unsigned int* __restrict__ gmax,
                          const float* __restrict__ gcnt,
                          const float* __restrict__ g_out, const float* __restrict__ b_out,
                          const float* __restrict__ m_out, const float* __restrict__ v_out,
                          float* __restrict__ out) {
  int g = blockIdx.x, t = threadIdx.x;
  float hn = gsum[g * HID + t] / fmaxf(gcnt[g], 1.0f);
  hn = (hn - m_out[t]) * rsqrtf(v_out[t] + BN_EPS) * g_out[t] + b_out[t];
  unsigned int key = gmax[g * HID + t];
  unsigned int u = (key & 0x80000000u) ? (key ^ 0x80000000u) : ~key;
  out[g * 2 * HID + t] = hn;
  out[g * 2 * HID + HID + t] = __uint_as_float(u);
}

// ================================ host ========================================

extern "C" void kernel_launch(void* const* d_in, const int* in_sizes, int n_in,
                              void* d_out, int out_size, void* d_ws, size_t ws_size,
                              hipStream_t stream) {
  const float* h_in   = (const float*)d_in[0];
  const float* e_in   = (const float*)d_in[1];
  const int*   src    = (const int*)d_in[2];
  const int*   dst    = (const int*)d_in[3];
  const int*   ng     = (const int*)d_in[4];
  const float* eW1_0  = (const float*)d_in[5];
  const float* eb1_0  = (const float*)d_in[6];
  const float* eW2_0  = (const float*)d_in[7];
  const float* eb2_0  = (const float*)d_in[8];
  const float* bias_0 = (const float*)d_in[9];
  const float* gamma_0= (const float*)d_in[10];
  const float* beta_0 = (const float*)d_in[11];
  const float* mean_0 = (const float*)d_in[12];
  const float* var_0  = (const float*)d_in[13];
  const float* eW1    = (const float*)d_in[14];
  const float* eb1    = (const float*)d_in[15];
  const float* eW2    = (const float*)d_in[16];
  const float* eb2    = (const float*)d_in[17];
  const float* biasL  = (const float*)d_in[18];
  const float* gammaL = (const float*)d_in[19];
  const float* betaL  = (const float*)d_in[20];
  const float* meanL  = (const float*)d_in[21];
  const float* varL   = (const float*)d_in[22];
  const float* g_out  = (const float*)d_in[23];
  const float* b_out  = (const float*)d_in[24];
  const float* m_out  = (const float*)d_in[25];
  const float* v_out  = (const float*)d_in[26];
  float* out = (float*)d_out;

  char* ws = (char*)d_ws;
  size_t off = 0;
  auto alloc = [&](size_t bytes) {
    void* pp = ws + off;
    off = (off + bytes + 255) & ~(size_t)255;
    return pp;
  };
  unsigned short* Z    = (unsigned short*)alloc((size_t)N_NODES * ZCOLS * 2);
  unsigned short* WbT0 = (unsigned short*)alloc((size_t)ZCOLS * 32 * 2);
  unsigned short* WbTL = (unsigned short*)alloc((size_t)3 * ZCOLS * HID * 2);
  unsigned short* xb0  = (unsigned short*)alloc((size_t)N_NODES * 32 * 2);
  unsigned short* xb   = (unsigned short*)alloc((size_t)N_NODES * HID * 2);
  float* gsum          = (float*)alloc((size_t)N_GRAPH * HID * 4);
  unsigned int* gmax   = (unsigned int*)alloc((size_t)N_GRAPH * HID * 4);
  float* gcnt          = (float*)alloc((size_t)N_GRAPH * 4);
  int* roff            = (int*)alloc((size_t)(N_NODES + 1) * 4);
  int* cursor          = (int*)alloc((size_t)N_NODES * 4);
  int* nodeorder       = (int*)alloc((size_t)N_NODES * 4);
  int* esrc            = (int*)alloc((size_t)N_EDGES * 4);
  float* ef6           = (float*)alloc((size_t)N_EDGES * E_DIMF * 4);

  PrepP P;
  P.eW2_0 = eW2_0; P.eb2_0 = eb2_0; P.eW2 = eW2; P.eb2 = eb2; P.h_in = h_in;
  P.dst = dst;
  P.WbT0 = WbT0; P.WbTL = WbTL; P.xb0 = xb0;
  P.roff = roff; P.cursor = cursor; P.nodeorder = nodeorder;
  P.gsum = gsum; P.gmax = gmax; P.gcnt = gcnt;

  // node 1: prep (CSR offsets + deg-sort, transposes, xb0, zero)
  prep_all<<<PREP_BLOCKS, 256, 0, stream>>>(P);

  // node 2: layer-0 gemm + fused scatter/pre-gather (grid.y==16 row)
  gemm_z<32, 3, 1><<<dim3(65, 17), 256, 2 * 128 * 32 * 2, stream>>>(
      xb0, WbT0, Z, dst, src, e_in, cursor, esrc, ef6);
  // node 3: layer-0 gather
  node_gather<0><<<N_NODES / 2, 256, 0, stream>>>(ef6, eW1_0, eb1_0, Z, esrc, roff,
                                                  nodeorder, bias_0, gamma_0, beta_0,
                                                  mean_0, var_0, xb, ng, gsum, gmax, gcnt);

  // nodes 4-9: layers 1..3
  for (int l = 0; l < 3; ++l) {
    gemm_z<128, 7, 0><<<dim3(65, 16), 256, 2 * 128 * 128 * 2, stream>>>(
        xb, WbTL + (size_t)l * ZCOLS * HID, Z, nullptr, nullptr, nullptr,
        nullptr, nullptr, nullptr);
    if (l < 2)
      node_gather<0><<<N_NODES / 2, 256, 0, stream>>>(
          ef6, eW1 + l * E_DIMF * EDGE_H, eb1 + l * EDGE_H, Z, esrc, roff,
          nodeorder, biasL + l * HID, gammaL + l * HID, betaL + l * HID,
          meanL + l * HID, varL + l * HID, xb, ng, gsum, gmax, gcnt);
    else
      node_gather<1><<<N_NODES / 2, 256, 0, stream>>>(
          ef6, eW1 + l * E_DIMF * EDGE_H, eb1 + l * EDGE_H, Z, esrc, roff,
          nodeorder, biasL + l * HID, gammaL + l * HID, betaL + l * HID,
          meanL + l * HID, varL + l * HID, xb, ng, gsum, gmax, gcnt);
  }

  // node 10: readout finale
  out_final<<<N_GRAPH, HID, 0, stream>>>(gsum, gmax, gcnt, g_out, b_out, m_out,
                                         v_out, out);
}